// Round 9
// baseline (428.652 us; speedup 1.0000x reference)
//
#include <hip/hip_runtime.h>

typedef __attribute__((ext_vector_type(8))) __bf16 bfx8;
typedef __attribute__((ext_vector_type(4))) float f32x4;

__device__ __forceinline__ float s2f(unsigned short s) {
  return __uint_as_float((unsigned int)s << 16);
}
// round-half-up bf16 convert (2 VALU ops; tie-only difference vs RNE)
__device__ __forceinline__ unsigned short f2s(float f) {
  return (unsigned short)((__float_as_uint(f) + 0x8000u) >> 16);
}

// ---------------------------------------------------------------------------
// Async MFMA GEMM core (global_load_lds staging, XOR-swizzled; R5-verified:
// SQ_LDS_BANK_CONFLICT == 0). Both operands [row][k] k-contiguous.
// D[m][n] = sum_k Ag[m][k]*Bg[n][k]. 256 thr = 4 waves 2x2.
// ---------------------------------------------------------------------------
template<int BM, int BN, int BK>
__device__ __forceinline__ void gemm_core_async(
    const unsigned short* __restrict__ Ag, int lda,
    const unsigned short* __restrict__ Bg, int ldb, int K,
    unsigned short* As, unsigned short* Bs, f32x4* acc)
{
  static_assert(BK == 64, "BK must be 64 (128B rows)");
  constexpr int WM = BM / 2, WN = BN / 2;
  constexpr int MT = WM / 16, NT = WN / 16;
  constexpr int SA = BM / 8, SB = BN / 8;   // 1024B segments per tile
  const int tid = threadIdx.x;
  const int lane = tid & 63, wave = tid >> 6;
  const int lr = lane & 15, quad = lane >> 4;
  const int sw = lr & 7;
  const int rl = lane >> 3;                  // row within segment (0..7)
  const int vg = (lane & 7) ^ rl;            // swizzled global vec index
  const int wm = (wave >> 1) * WM, wn = (wave & 1) * WN;

  for (int k0 = 0; k0 < K; k0 += BK) {
#pragma unroll
    for (int s = wave; s < SA; s += 4) {
      const unsigned short* g = Ag + (size_t)(s * 8 + rl) * lda + k0 + vg * 8;
      __builtin_amdgcn_global_load_lds(
          (__attribute__((address_space(1))) void*)g,
          (__attribute__((address_space(3))) void*)(As + s * 512), 16, 0, 0);
    }
#pragma unroll
    for (int s = wave; s < SB; s += 4) {
      const unsigned short* g = Bg + (size_t)(s * 8 + rl) * ldb + k0 + vg * 8;
      __builtin_amdgcn_global_load_lds(
          (__attribute__((address_space(1))) void*)g,
          (__attribute__((address_space(3))) void*)(Bs + s * 512), 16, 0, 0);
    }
    __syncthreads();
#pragma unroll
    for (int kk = 0; kk < BK; kk += 32) {
      const int kv = kk >> 3;                // 0 or 4
      bfx8 af[MT], bfr[NT];
#pragma unroll
      for (int i = 0; i < MT; ++i)
        af[i] = *(const bfx8*)(As + (wm + i * 16 + lr) * BK
                               + (((quad + kv) ^ sw) << 3));
#pragma unroll
      for (int j = 0; j < NT; ++j)
        bfr[j] = *(const bfx8*)(Bs + (wn + j * 16 + lr) * BK
                                + (((quad + kv) ^ sw) << 3));
#pragma unroll
      for (int i = 0; i < MT; ++i)
#pragma unroll
        for (int j = 0; j < NT; ++j)
          acc[i * NT + j] = __builtin_amdgcn_mfma_f32_16x16x32_bf16(
              af[i], bfr[j], acc[i * NT + j], 0, 0, 0);
    }
    __syncthreads();
  }
}

// ---------------------------------------------------------------------------
// k_pre: fused x transpose (fp32 [4][512][4096] -> bf16 x_t [4][4096][512],
// blocks 0..2047) and weight converts (blocks 2048..3071).
// ---------------------------------------------------------------------------
__global__ __launch_bounds__(256) void k_pre(
    const float* __restrict__ x, unsigned short* __restrict__ xt,
    const float* __restrict__ wq, const float* __restrict__ wk,
    const float* __restrict__ wv, const float* __restrict__ wW,
    unsigned short* __restrict__ wqk, unsigned short* __restrict__ wvb,
    unsigned short* __restrict__ wWb)
{
  const int bid = blockIdx.x, tid = threadIdx.x;
  if (bid < 2048) {
    __shared__ float t[64][65];
    const int b = bid >> 9, c0 = ((bid >> 6) & 7) * 64, n0 = (bid & 63) * 64;
    const float* xb = x + ((size_t)b << 21);
    const int hi = tid >> 6, lo = tid & 63;
#pragma unroll
    for (int p = 0; p < 16; ++p)
      t[hi + p * 4][lo] = xb[(size_t)(c0 + hi + p * 4) * 4096 + n0 + lo];
    __syncthreads();
    unsigned short* xtb = xt + ((size_t)b << 21);
#pragma unroll
    for (int p = 0; p < 16; ++p)
      xtb[(size_t)(n0 + hi + p * 4) * 512 + c0 + lo] = f2s(t[lo][hi + p * 4]);
  } else {
    int i = (bid - 2048) * 256 + tid;              // i < 262144
    wqk[i] = f2s(i < 131072 ? wq[i] : wk[i - 131072]);
    if (i < 131072) { wvb[i] = f2s(wv[i]); wWb[i] = f2s(wW[i]); }
  }
}

// ---------------------------------------------------------------------------
// k_qkv: fused QK GEMM (+fp32 BN stats partials in epilogue) and V GEMM.
// ---------------------------------------------------------------------------
__global__ __launch_bounds__(256) void k_qkv(
    const unsigned short* __restrict__ xt, const unsigned short* __restrict__ wqk,
    const unsigned short* __restrict__ wvb, const float* __restrict__ bv,
    unsigned short* __restrict__ zt, unsigned short* __restrict__ v,
    float* __restrict__ stat)
{
  __shared__ __align__(16) unsigned short As[128 * 64], Bs[128 * 64];
  f32x4 acc[16] = {};
  const int b = blockIdx.z, n0 = blockIdx.x * 128, t = blockIdx.y;
  const int lane = threadIdx.x & 63, wave = threadIdx.x >> 6;
  const int lr = lane & 15, quad = lane >> 4;
  const int wm = (wave >> 1) * 64, wn = (wave & 1) * 64;

  if (t < 4) {
    const int o0 = t * 128;
    gemm_core_async<128, 128, 64>(xt + ((size_t)b * 4096 + n0) * 512, 512,
                                  wqk + (size_t)o0 * 512, 512, 512, As, Bs, acc);
    float s[4] = {}, ss[4] = {};
#pragma unroll
    for (int i = 0; i < 4; ++i)
#pragma unroll
      for (int j = 0; j < 4; ++j)
#pragma unroll
        for (int r = 0; r < 4; ++r) {
          float a = acc[i * 4 + j][r];
          int row = wm + i * 16 + quad * 4 + r, col = wn + j * 16 + lr;
          zt[((size_t)b * 4096 + n0 + row) * 512 + o0 + col] = f2s(a);
          s[j] += a; ss[j] += a * a;
        }
#pragma unroll
    for (int j = 0; j < 4; ++j) {
      s[j]  += __shfl_down(s[j], 32, 64);  s[j]  += __shfl_down(s[j], 16, 64);
      ss[j] += __shfl_down(ss[j], 32, 64); ss[j] += __shfl_down(ss[j], 16, 64);
      if (quad == 0) {
        int o = o0 + wn + j * 16 + lr;
        atomicAdd(&stat[o * 2], s[j]);
        atomicAdd(&stat[o * 2 + 1], ss[j]);
      }
    }
  } else {
    const int cv0 = (t - 4) * 128;
    gemm_core_async<128, 128, 64>(wvb + (size_t)cv0 * 512, 512,
                                  xt + ((size_t)b * 4096 + n0) * 512, 512, 512,
                                  As, Bs, acc);
#pragma unroll
    for (int i = 0; i < 4; ++i)
#pragma unroll
      for (int j = 0; j < 4; ++j)
#pragma unroll
        for (int r = 0; r < 4; ++r) {
          int row = wm + i * 16 + quad * 4 + r, col = wn + j * 16 + lr;
          v[((size_t)b * 256 + cv0 + row) * 4096 + n0 + col] =
              f2s(acc[i * 4 + j][r] + bv[cv0 + row]);
        }
  }
}

// ---------------------------------------------------------------------------
// BN+ReLU: q_t[n][c] / k_t[n][c] bf16 from z_t columns.
// ---------------------------------------------------------------------------
__global__ __launch_bounds__(256) void k_bnrelu(
    const unsigned short* __restrict__ zt, const float* __restrict__ stats_raw,
    const float* __restrict__ gq, const float* __restrict__ betaq,
    const float* __restrict__ gk, const float* __restrict__ betak,
    unsigned short* __restrict__ qt, unsigned short* __restrict__ kt)
{
  const int t = threadIdx.x;
  const float mA = stats_raw[t * 2] * (1.f / 16384.f);
  const float vA = stats_raw[t * 2 + 1] * (1.f / 16384.f) - mA * mA;
  const float scA = rsqrtf(vA + 1e-5f) * gq[t], beA = betaq[t];
  const float mB = stats_raw[(t + 256) * 2] * (1.f / 16384.f);
  const float vB = stats_raw[(t + 256) * 2 + 1] * (1.f / 16384.f) - mB * mB;
  const float scB = rsqrtf(vB + 1e-5f) * gk[t], beB = betak[t];
  const int r0 = blockIdx.x * 64;
  for (int r = r0; r < r0 + 64; ++r) {
    float a = s2f(zt[(size_t)r * 512 + t]);
    qt[(size_t)r * 256 + t] = f2s(fmaxf((a - mA) * scA + beA, 0.f));
    float c = s2f(zt[(size_t)r * 512 + t + 256]);
    kt[(size_t)r * 256 + t] = f2s(fmaxf((c - mB) * scB + beB, 0.f));
  }
}

// ---------------------------------------------------------------------------
// k_att (v2): flash attention, split-K over m, streamed operands direct from
// global (no LDS staging for qt/v -> LDS = kt 32K + P_s 9K = 41 KB ->
// 3 blocks/CU with __launch_bounds__(256,3)).
// Block: (n-tile 64, m-strip 1024, all 256 c, batch b). Grid (64,4,4).
// Fixed-shift softmax (q,k>=0): p = exp2(S*C1 + C0); no online rescale.
// Per chunk (m 64): QK (B-frags = 16B/lane direct loads of qt, 4 quads
// consume one 64B line -> fully coalesced, L1/L2-hot), exp -> P_s (LDS,
// stride 72), barrier, PV (A from P_s, B = direct v loads), barrier.
// Row sums accumulate in REGISTERS across chunks; one LDS reduce at end.
// Outputs: opart bf16 partials + lpart row sums; k_red reduces 4 splits.
// ---------------------------------------------------------------------------
__global__ __launch_bounds__(256, 3) void k_att(
    const unsigned short* __restrict__ qt, const unsigned short* __restrict__ kt,
    const unsigned short* __restrict__ vglob,
    unsigned short* __restrict__ opart, float* __restrict__ lpart)
{
  __shared__ __align__(16) unsigned short kt_s[64 * 256];  // 32 KB
  __shared__ __align__(16) unsigned short P_s[64 * 72];    //  9 KB
  __shared__ float lrow[64];

  const int n0 = blockIdx.x * 64;
  const int split = blockIdx.y;
  const int b = blockIdx.z;
  const int tid = threadIdx.x, lane = tid & 63, wave = tid >> 6;
  const int lr = lane & 15, quad = lane >> 4;
  const int sw = lr & 7;
  const int wn_n = (wave >> 1) * 32;     // n-half (32 rows, QK & PV & output)
  const int wn_m = (wave & 1) * 32;      // m-half in QK
  const int wn_c = (wave & 1) * 128;     // c-half in PV

  const unsigned short* KT = kt + ((size_t)b * 4096 + n0) * 256;
  const unsigned short* QT = qt + ((size_t)b * 4096 + split * 1024) * 256;
  const unsigned short* V  = vglob + (size_t)b * 256 * 4096 + split * 1024;

  // stage kt tile once (R8-verified wide-row swizzle: vec = sl32 ^ (row&7))
  {
    const int rl2 = lane >> 5, sl32 = lane & 31;
#pragma unroll
    for (int s = wave; s < 32; s += 4) {
      int row = 2 * s + rl2;
      __builtin_amdgcn_global_load_lds(
          (__attribute__((address_space(1))) void*)(KT + (size_t)row * 256 + ((sl32 ^ (row & 7)) << 3)),
          (__attribute__((address_space(3))) void*)(kt_s + s * 512), 16, 0, 0);
    }
  }
  if (tid < 64) lrow[tid] = 0.f;

  f32x4 acc_o[16] = {};
  float rsum[8] = {};                    // [i][r] row-sum accumulators
  const float C1 = 0.0625f * 1.44269504f;
  const float C0 = -20.0f * 1.44269504f;
  __syncthreads();                       // kt_s ready (barrier drains vmcnt)

  for (int mc = 0; mc < 16; ++mc) {
    const int mbase = mc * 64;
    // ---- QK: S[64n][64m], K=256; A from kt_s, B direct from global ----
    f32x4 accs[4] = {};
#pragma unroll
    for (int ks = 0; ks < 8; ++ks) {
      bfx8 ak[2], bq[2];
#pragma unroll
      for (int i = 0; i < 2; ++i)
        ak[i] = *(const bfx8*)(kt_s + (wn_n + i * 16 + lr) * 256
                               + (((ks * 4 + quad) ^ sw) << 3));
#pragma unroll
      for (int j = 0; j < 2; ++j)
        bq[j] = *(const bfx8*)(QT + (size_t)(mbase + wn_m + j * 16 + lr) * 256
                               + ks * 32 + quad * 8);
#pragma unroll
      for (int i = 0; i < 2; ++i)
#pragma unroll
        for (int j = 0; j < 2; ++j)
          accs[i * 2 + j] = __builtin_amdgcn_mfma_f32_16x16x32_bf16(
              ak[i], bq[j], accs[i * 2 + j], 0, 0, 0);
    }
    // ---- exp -> P_s + register row sums ----
#pragma unroll
    for (int i = 0; i < 2; ++i)
#pragma unroll
      for (int r = 0; r < 4; ++r) {
        int row = wn_n + i * 16 + quad * 4 + r;
#pragma unroll
        for (int j = 0; j < 2; ++j) {
          float p = __builtin_amdgcn_exp2f(fmaf(accs[i * 2 + j][r], C1, C0));
          P_s[row * 72 + wn_m + j * 16 + lr] = f2s(p);
          rsum[i * 4 + r] += p;
        }
      }
    __syncthreads();                     // P_s complete (both m-half waves)
    // ---- PV: ctx[64n][256c] += P_s * v, K=64; B direct from global ----
#pragma unroll
    for (int ks = 0; ks < 2; ++ks) {
      bfx8 ap[2], bv_[8];
#pragma unroll
      for (int i = 0; i < 2; ++i)
        ap[i] = *(const bfx8*)(P_s + (wn_n + i * 16 + lr) * 72
                               + (ks * 4 + quad) * 8);
#pragma unroll
      for (int j = 0; j < 8; ++j)
        bv_[j] = *(const bfx8*)(V + (size_t)(wn_c + j * 16 + lr) * 4096
                                + mbase + ks * 32 + quad * 8);
#pragma unroll
      for (int i = 0; i < 2; ++i)
#pragma unroll
        for (int j = 0; j < 8; ++j)
          acc_o[i * 8 + j] = __builtin_amdgcn_mfma_f32_16x16x32_bf16(
              ap[i], bv_[j], acc_o[i * 8 + j], 0, 0, 0);
    }
    __syncthreads();                     // P_s reads done before next rewrite
  }

  // ---- row sums: lane-reduce over lr, combine m-half waves via lrow ----
#pragma unroll
  for (int t = 0; t < 8; ++t) {
    rsum[t] += __shfl_down(rsum[t], 8, 16);
    rsum[t] += __shfl_down(rsum[t], 4, 16);
    rsum[t] += __shfl_down(rsum[t], 2, 16);
    rsum[t] += __shfl_down(rsum[t], 1, 16);
  }
  if (lr == 0) {
#pragma unroll
    for (int i = 0; i < 2; ++i)
#pragma unroll
      for (int r = 0; r < 4; ++r)
        atomicAdd(&lrow[wn_n + i * 16 + quad * 4 + r], rsum[i * 4 + r]);
  }
  __syncthreads();
  if (tid < 64)
    lpart[((size_t)split * 4 + b) * 4096 + n0 + tid] = lrow[tid];
  unsigned short* op = opart + (((size_t)split * 4 + b) * 4096 + n0) * 256;
#pragma unroll
  for (int i = 0; i < 2; ++i)
#pragma unroll
    for (int r = 0; r < 4; ++r) {
      int row = wn_n + i * 16 + quad * 4 + r;
#pragma unroll
      for (int j = 0; j < 8; ++j)
        op[(size_t)row * 256 + wn_c + j * 16 + lr] = f2s(acc_o[i * 8 + j][r]);
    }
}

// ---------------------------------------------------------------------------
// k_red: ctx[b,n][c] = (sum_s opart[s][b][n][c]) / (sum_s lpart[s][b][n])
// grid 16384 (b*4096+n) x 256 (c).
// ---------------------------------------------------------------------------
__global__ __launch_bounds__(256) void k_red(
    const unsigned short* __restrict__ opart, const float* __restrict__ lpart,
    unsigned short* __restrict__ ctx)
{
  const int g = blockIdx.x, c = threadIdx.x;     // g = b*4096 + n
  const int b = g >> 12, n = g & 4095;
  float s = 0.f, l = 0.f;
#pragma unroll
  for (int sp = 0; sp < 4; ++sp) {
    s += s2f(opart[(((size_t)sp * 4 + b) * 4096 + n) * 256 + c]);
    l += lpart[((size_t)sp * 4 + b) * 4096 + n];
  }
  ctx[(size_t)g * 256 + c] = f2s(s / l);
}

// ---------------------------------------------------------------------------
// Out: out[b][o][n] = sum_cv wW[o][cv] ctx[b,n][cv] + bW[o] + x[b][o][n]
// ---------------------------------------------------------------------------
__global__ __launch_bounds__(256) void k_out(
    const unsigned short* __restrict__ wWb, const float* __restrict__ bW,
    const unsigned short* __restrict__ ctx, const float* __restrict__ x,
    float* __restrict__ out)
{
  __shared__ __align__(16) unsigned short As[128 * 64], Bs[128 * 64];
  f32x4 acc[16] = {};
  const int b = blockIdx.z, n0 = blockIdx.x * 128, o0 = blockIdx.y * 128;
  gemm_core_async<128, 128, 64>(wWb + (size_t)o0 * 256, 256,
                                ctx + ((size_t)b * 4096 + n0) * 256, 256, 256,
                                As, Bs, acc);
  const int lane = threadIdx.x & 63, wave = threadIdx.x >> 6;
  const int lr = lane & 15, quad = lane >> 4;
  const int wm = (wave >> 1) * 64, wn = (wave & 1) * 64;
#pragma unroll
  for (int i = 0; i < 4; ++i)
#pragma unroll
    for (int j = 0; j < 4; ++j)
#pragma unroll
      for (int r = 0; r < 4; ++r) {
        int row = wm + i * 16 + quad * 4 + r, col = wn + j * 16 + lr;
        size_t idx = ((size_t)b * 512 + o0 + row) * 4096 + n0 + col;
        out[idx] = acc[i * 4 + j][r] + bW[o0 + row] + x[idx];
      }
}

// ---------------------------------------------------------------------------
extern "C" void kernel_launch(void* const* d_in, const int* in_sizes, int n_in,
                              void* d_out, int out_size, void* d_ws, size_t ws_size,
                              hipStream_t stream)
{
  const float* x     = (const float*)d_in[0];
  const float* wq    = (const float*)d_in[1];
  // d_in[2] = bq: cancelled exactly by BN mean-subtraction
  const float* gq    = (const float*)d_in[3];
  const float* betaq = (const float*)d_in[4];
  const float* wk    = (const float*)d_in[5];
  // d_in[6] = bk: cancelled
  const float* gk    = (const float*)d_in[7];
  const float* betak = (const float*)d_in[8];
  const float* wv    = (const float*)d_in[9];
  const float* bv    = (const float*)d_in[10];
  const float* wW    = (const float*)d_in[11];
  const float* bW    = (const float*)d_in[12];
  float* out = (float*)d_out;

  // workspace layout (ws_size = 256 MiB)
  char* ws = (char*)d_ws;
  unsigned short* qt   = (unsigned short*)(ws);              //  8 MiB [4*4096,256]
  unsigned short* kt   = (unsigned short*)(ws + 8388608);    //  8 MiB
  unsigned short* v    = (unsigned short*)(ws + 16777216);   //  8 MiB [4,256,4096]
  unsigned short* ctx  = (unsigned short*)(ws + 25165824);   //  8 MiB [4*4096,256]
  unsigned short* wqk  = (unsigned short*)(ws + 33554432);   // 512 KiB [512,512]
  unsigned short* wvb  = (unsigned short*)(ws + 34078720);   // 256 KiB [256,512]
  unsigned short* wWb  = (unsigned short*)(ws + 34340864);   // 256 KiB [512,256]
  float*          stat = (float*)         (ws + 34603008);   //   4 KiB
  unsigned short* xt   = (unsigned short*)(ws + 35651584);   // 16 MiB
  unsigned short* zt   = (unsigned short*)(ws + 52428800);   // 16 MiB
  unsigned short* opart= (unsigned short*)(ws + 69206016);   // 32 MiB [16,4096,256] bf16
  float*          lpart= (float*)         (ws + 102760448);  // 256 KiB [16,4096]

  (void)hipMemsetAsync(stat, 0, 4096, stream);
  k_pre   <<<3072, 256, 0, stream>>>(x, xt, wq, wk, wv, wW, wqk, wvb, wWb);
  k_qkv   <<<dim3(32, 6, 4), 256, 0, stream>>>(xt, wqk, wvb, bv, zt, v, stat);
  k_bnrelu<<<256, 256, 0, stream>>>(zt, stat, gq, betaq, gk, betak, qt, kt);
  k_att   <<<dim3(64, 4, 4), 256, 0, stream>>>(qt, kt, v, opart, lpart);
  k_red   <<<16384, 256, 0, stream>>>(opart, lpart, ctx);
  k_out   <<<dim3(32, 4, 4), 256, 0, stream>>>(wWb, bW, ctx, x, out);
}

// Round 10
// 302.789 us; speedup vs baseline: 1.4157x; 1.4157x over previous
//
#include <hip/hip_runtime.h>

typedef __attribute__((ext_vector_type(8))) __bf16 bfx8;
typedef __attribute__((ext_vector_type(4))) float f32x4;

__device__ __forceinline__ float s2f(unsigned short s) {
  return __uint_as_float((unsigned int)s << 16);
}
// round-half-up bf16 convert (2 VALU ops; tie-only difference vs RNE)
__device__ __forceinline__ unsigned short f2s(float f) {
  return (unsigned short)((__float_as_uint(f) + 0x8000u) >> 16);
}

// ---------------------------------------------------------------------------
// Async MFMA GEMM core (global_load_lds staging, XOR-swizzled; R5-verified:
// SQ_LDS_BANK_CONFLICT == 0). Both operands [row][k] k-contiguous.
// D[m][n] = sum_k Ag[m][k]*Bg[n][k]. 256 thr = 4 waves 2x2.
// ---------------------------------------------------------------------------
template<int BM, int BN, int BK>
__device__ __forceinline__ void gemm_core_async(
    const unsigned short* __restrict__ Ag, int lda,
    const unsigned short* __restrict__ Bg, int ldb, int K,
    unsigned short* As, unsigned short* Bs, f32x4* acc)
{
  static_assert(BK == 64, "BK must be 64 (128B rows)");
  constexpr int WM = BM / 2, WN = BN / 2;
  constexpr int MT = WM / 16, NT = WN / 16;
  constexpr int SA = BM / 8, SB = BN / 8;   // 1024B segments per tile
  const int tid = threadIdx.x;
  const int lane = tid & 63, wave = tid >> 6;
  const int lr = lane & 15, quad = lane >> 4;
  const int sw = lr & 7;
  const int rl = lane >> 3;                  // row within segment (0..7)
  const int vg = (lane & 7) ^ rl;            // swizzled global vec index
  const int wm = (wave >> 1) * WM, wn = (wave & 1) * WN;

  for (int k0 = 0; k0 < K; k0 += BK) {
#pragma unroll
    for (int s = wave; s < SA; s += 4) {
      const unsigned short* g = Ag + (size_t)(s * 8 + rl) * lda + k0 + vg * 8;
      __builtin_amdgcn_global_load_lds(
          (__attribute__((address_space(1))) void*)g,
          (__attribute__((address_space(3))) void*)(As + s * 512), 16, 0, 0);
    }
#pragma unroll
    for (int s = wave; s < SB; s += 4) {
      const unsigned short* g = Bg + (size_t)(s * 8 + rl) * ldb + k0 + vg * 8;
      __builtin_amdgcn_global_load_lds(
          (__attribute__((address_space(1))) void*)g,
          (__attribute__((address_space(3))) void*)(Bs + s * 512), 16, 0, 0);
    }
    __syncthreads();
#pragma unroll
    for (int kk = 0; kk < BK; kk += 32) {
      const int kv = kk >> 3;                // 0 or 4
      bfx8 af[MT], bfr[NT];
#pragma unroll
      for (int i = 0; i < MT; ++i)
        af[i] = *(const bfx8*)(As + (wm + i * 16 + lr) * BK
                               + (((quad + kv) ^ sw) << 3));
#pragma unroll
      for (int j = 0; j < NT; ++j)
        bfr[j] = *(const bfx8*)(Bs + (wn + j * 16 + lr) * BK
                                + (((quad + kv) ^ sw) << 3));
#pragma unroll
      for (int i = 0; i < MT; ++i)
#pragma unroll
        for (int j = 0; j < NT; ++j)
          acc[i * NT + j] = __builtin_amdgcn_mfma_f32_16x16x32_bf16(
              af[i], bfr[j], acc[i * NT + j], 0, 0, 0);
    }
    __syncthreads();
  }
}

// ---------------------------------------------------------------------------
// k_pre: fused x transpose (fp32 [4][512][4096] -> bf16 x_t [4][4096][512],
// blocks 0..2047) and weight converts (blocks 2048..3071).
// ---------------------------------------------------------------------------
__global__ __launch_bounds__(256) void k_pre(
    const float* __restrict__ x, unsigned short* __restrict__ xt,
    const float* __restrict__ wq, const float* __restrict__ wk,
    const float* __restrict__ wv, const float* __restrict__ wW,
    unsigned short* __restrict__ wqk, unsigned short* __restrict__ wvb,
    unsigned short* __restrict__ wWb)
{
  const int bid = blockIdx.x, tid = threadIdx.x;
  if (bid < 2048) {
    __shared__ float t[64][65];
    const int b = bid >> 9, c0 = ((bid >> 6) & 7) * 64, n0 = (bid & 63) * 64;
    const float* xb = x + ((size_t)b << 21);
    const int hi = tid >> 6, lo = tid & 63;
#pragma unroll
    for (int p = 0; p < 16; ++p)
      t[hi + p * 4][lo] = xb[(size_t)(c0 + hi + p * 4) * 4096 + n0 + lo];
    __syncthreads();
    unsigned short* xtb = xt + ((size_t)b << 21);
#pragma unroll
    for (int p = 0; p < 16; ++p)
      xtb[(size_t)(n0 + hi + p * 4) * 512 + c0 + lo] = f2s(t[lo][hi + p * 4]);
  } else {
    int i = (bid - 2048) * 256 + tid;              // i < 262144
    wqk[i] = f2s(i < 131072 ? wq[i] : wk[i - 131072]);
    if (i < 131072) { wvb[i] = f2s(wv[i]); wWb[i] = f2s(wW[i]); }
  }
}

// ---------------------------------------------------------------------------
// k_qkv: fused QK GEMM (+fp32 BN stats partials in epilogue) and V GEMM.
// ---------------------------------------------------------------------------
__global__ __launch_bounds__(256) void k_qkv(
    const unsigned short* __restrict__ xt, const unsigned short* __restrict__ wqk,
    const unsigned short* __restrict__ wvb, const float* __restrict__ bv,
    unsigned short* __restrict__ zt, unsigned short* __restrict__ v,
    float* __restrict__ stat)
{
  __shared__ __align__(16) unsigned short As[128 * 64], Bs[128 * 64];
  f32x4 acc[16] = {};
  const int b = blockIdx.z, n0 = blockIdx.x * 128, t = blockIdx.y;
  const int lane = threadIdx.x & 63, wave = threadIdx.x >> 6;
  const int lr = lane & 15, quad = lane >> 4;
  const int wm = (wave >> 1) * 64, wn = (wave & 1) * 64;

  if (t < 4) {
    const int o0 = t * 128;
    gemm_core_async<128, 128, 64>(xt + ((size_t)b * 4096 + n0) * 512, 512,
                                  wqk + (size_t)o0 * 512, 512, 512, As, Bs, acc);
    float s[4] = {}, ss[4] = {};
#pragma unroll
    for (int i = 0; i < 4; ++i)
#pragma unroll
      for (int j = 0; j < 4; ++j)
#pragma unroll
        for (int r = 0; r < 4; ++r) {
          float a = acc[i * 4 + j][r];
          int row = wm + i * 16 + quad * 4 + r, col = wn + j * 16 + lr;
          zt[((size_t)b * 4096 + n0 + row) * 512 + o0 + col] = f2s(a);
          s[j] += a; ss[j] += a * a;
        }
#pragma unroll
    for (int j = 0; j < 4; ++j) {
      s[j]  += __shfl_down(s[j], 32, 64);  s[j]  += __shfl_down(s[j], 16, 64);
      ss[j] += __shfl_down(ss[j], 32, 64); ss[j] += __shfl_down(ss[j], 16, 64);
      if (quad == 0) {
        int o = o0 + wn + j * 16 + lr;
        atomicAdd(&stat[o * 2], s[j]);
        atomicAdd(&stat[o * 2 + 1], ss[j]);
      }
    }
  } else {
    const int cv0 = (t - 4) * 128;
    gemm_core_async<128, 128, 64>(wvb + (size_t)cv0 * 512, 512,
                                  xt + ((size_t)b * 4096 + n0) * 512, 512, 512,
                                  As, Bs, acc);
#pragma unroll
    for (int i = 0; i < 4; ++i)
#pragma unroll
      for (int j = 0; j < 4; ++j)
#pragma unroll
        for (int r = 0; r < 4; ++r) {
          int row = wm + i * 16 + quad * 4 + r, col = wn + j * 16 + lr;
          v[((size_t)b * 256 + cv0 + row) * 4096 + n0 + col] =
              f2s(acc[i * 4 + j][r] + bv[cv0 + row]);
        }
  }
}

// ---------------------------------------------------------------------------
// BN+ReLU: q_t[n][c] / k_t[n][c] bf16 from z_t columns.
// grid 1024 x 16 rows (4 blocks/CU; was 256 blocks = 1/CU at ~15 us).
// ---------------------------------------------------------------------------
__global__ __launch_bounds__(256) void k_bnrelu(
    const unsigned short* __restrict__ zt, const float* __restrict__ stats_raw,
    const float* __restrict__ gq, const float* __restrict__ betaq,
    const float* __restrict__ gk, const float* __restrict__ betak,
    unsigned short* __restrict__ qt, unsigned short* __restrict__ kt)
{
  const int t = threadIdx.x;
  const float mA = stats_raw[t * 2] * (1.f / 16384.f);
  const float vA = stats_raw[t * 2 + 1] * (1.f / 16384.f) - mA * mA;
  const float scA = rsqrtf(vA + 1e-5f) * gq[t], beA = betaq[t];
  const float mB = stats_raw[(t + 256) * 2] * (1.f / 16384.f);
  const float vB = stats_raw[(t + 256) * 2 + 1] * (1.f / 16384.f) - mB * mB;
  const float scB = rsqrtf(vB + 1e-5f) * gk[t], beB = betak[t];
  const int r0 = blockIdx.x * 16;
  for (int r = r0; r < r0 + 16; ++r) {
    float a = s2f(zt[(size_t)r * 512 + t]);
    qt[(size_t)r * 256 + t] = f2s(fmaxf((a - mA) * scA + beA, 0.f));
    float c = s2f(zt[(size_t)r * 512 + t + 256]);
    kt[(size_t)r * 256 + t] = f2s(fmaxf((c - mB) * scB + beB, 0.f));
  }
}

// ---------------------------------------------------------------------------
// Scores+exp (all batches): P[b][n][m] = exp(s/16 - 20),
// s = sum_c kt[b,n][c] qt[b,m][c]. Fixed-shift softmax (q,k>=0 -> s in
// [0,~30]; shift-invariant, never over/underflows). exp via v_exp_f32 on
// exp2-domain fma; row sums from fp32 p.
// ---------------------------------------------------------------------------
__global__ __launch_bounds__(256) void k_sc(
    const unsigned short* __restrict__ qt, const unsigned short* __restrict__ kt,
    unsigned short* __restrict__ P, float* __restrict__ lsum)
{
  __shared__ __align__(16) unsigned short As[128 * 64], Bs[128 * 64];
  f32x4 acc[16] = {};
  const int b = blockIdx.z, m0 = blockIdx.x * 128, n0 = blockIdx.y * 128;
  gemm_core_async<128, 128, 64>(kt + ((size_t)b * 4096 + n0) * 256, 256,
                                qt + ((size_t)b * 4096 + m0) * 256, 256, 256,
                                As, Bs, acc);
  const int lane = threadIdx.x & 63, wave = threadIdx.x >> 6;
  const int lr = lane & 15, quad = lane >> 4;
  const int wm = (wave >> 1) * 64, wn = (wave & 1) * 64;
  unsigned short* Pb = P + (size_t)b * 16777216;
  float* l = lsum + b * 4096;
  const float C1 = 0.0625f * 1.44269504f;    // log2(e)/16
  const float C0 = -20.0f * 1.44269504f;     // -20*log2(e)
#pragma unroll
  for (int i = 0; i < 4; ++i)
#pragma unroll
    for (int r = 0; r < 4; ++r) {
      int row = wm + i * 16 + quad * 4 + r;
      float rs = 0.f;
#pragma unroll
      for (int j = 0; j < 4; ++j) {
        float p = __builtin_amdgcn_exp2f(fmaf(acc[i * 4 + j][r], C1, C0));
        Pb[(size_t)(n0 + row) * 4096 + m0 + wn + j * 16 + lr] = f2s(p);
        rs += p;
      }
      rs += __shfl_down(rs, 8, 16);
      rs += __shfl_down(rs, 4, 16);
      rs += __shfl_down(rs, 2, 16);
      rs += __shfl_down(rs, 1, 16);
      if (lr == 0) atomicAdd(&l[n0 + row], rs);
    }
}

// ---------------------------------------------------------------------------
// Context partials (all batches, K-split 4): m-range [split*1024, +1024):
//   opart[split][b][n][c] = sum_m P[b][n][m] v[b][c][m]   (bf16 partials)
// grid (4 splits, 32 n-tiles, b*2+ctile), tile 128n x 128c -> 1024 blocks.
// ---------------------------------------------------------------------------
__global__ __launch_bounds__(256) void k_cx(
    const unsigned short* __restrict__ P, const unsigned short* __restrict__ v,
    unsigned short* __restrict__ opart)
{
  __shared__ __align__(16) unsigned short As[128 * 64], Bs[128 * 64];
  f32x4 acc[16] = {};
  const int split = blockIdx.x, n0 = blockIdx.y * 128;
  const int b = blockIdx.z >> 1, c0 = (blockIdx.z & 1) * 128;
  const int m0 = split * 1024;
  gemm_core_async<128, 128, 64>(
      P + ((size_t)b * 4096 + n0) * 4096 + m0, 4096,
      v + ((size_t)b * 256 + c0) * 4096 + m0, 4096, 1024, As, Bs, acc);
  const int lane = threadIdx.x & 63, wave = threadIdx.x >> 6;
  const int lr = lane & 15, quad = lane >> 4;
  const int wm = (wave >> 1) * 64, wn = (wave & 1) * 64;
  unsigned short* op = opart + (size_t)(split * 4 + b) * 1048576;
#pragma unroll
  for (int i = 0; i < 4; ++i)
#pragma unroll
    for (int j = 0; j < 4; ++j)
#pragma unroll
      for (int r = 0; r < 4; ++r) {
        int row = wm + i * 16 + quad * 4 + r, col = wn + j * 16 + lr;
        op[(size_t)(n0 + row) * 256 + c0 + col] = f2s(acc[i * 4 + j][r]);
      }
}

// ---------------------------------------------------------------------------
// k_red: ctx[b,n][c] = (sum_s opart[s][b][n][c]) / lsum[b][n]
// grid 16384 (b*4096+n) x 256 (c). Coalesced.
// ---------------------------------------------------------------------------
__global__ __launch_bounds__(256) void k_red(
    const unsigned short* __restrict__ opart, const float* __restrict__ lsum,
    unsigned short* __restrict__ ctx)
{
  const int g = blockIdx.x, c = threadIdx.x;     // g = b*4096 + n
  const int b = g >> 12, n = g & 4095;
  float s = 0.f;
#pragma unroll
  for (int sp = 0; sp < 4; ++sp)
    s += s2f(opart[(((size_t)sp * 4 + b) * 4096 + n) * 256 + c]);
  ctx[(size_t)g * 256 + c] = f2s(s / lsum[g]);
}

// ---------------------------------------------------------------------------
// Out: out[b][o][n] = sum_cv wW[o][cv] ctx[b,n][cv] + bW[o] + x[b][o][n]
// ---------------------------------------------------------------------------
__global__ __launch_bounds__(256) void k_out(
    const unsigned short* __restrict__ wWb, const float* __restrict__ bW,
    const unsigned short* __restrict__ ctx, const float* __restrict__ x,
    float* __restrict__ out)
{
  __shared__ __align__(16) unsigned short As[128 * 64], Bs[128 * 64];
  f32x4 acc[16] = {};
  const int b = blockIdx.z, n0 = blockIdx.x * 128, o0 = blockIdx.y * 128;
  gemm_core_async<128, 128, 64>(wWb + (size_t)o0 * 256, 256,
                                ctx + ((size_t)b * 4096 + n0) * 256, 256, 256,
                                As, Bs, acc);
  const int lane = threadIdx.x & 63, wave = threadIdx.x >> 6;
  const int lr = lane & 15, quad = lane >> 4;
  const int wm = (wave >> 1) * 64, wn = (wave & 1) * 64;
#pragma unroll
  for (int i = 0; i < 4; ++i)
#pragma unroll
    for (int j = 0; j < 4; ++j)
#pragma unroll
      for (int r = 0; r < 4; ++r) {
        int row = wm + i * 16 + quad * 4 + r, col = wn + j * 16 + lr;
        size_t idx = ((size_t)b * 512 + o0 + row) * 4096 + n0 + col;
        out[idx] = acc[i * 4 + j][r] + bW[o0 + row] + x[idx];
      }
}

// ---------------------------------------------------------------------------
extern "C" void kernel_launch(void* const* d_in, const int* in_sizes, int n_in,
                              void* d_out, int out_size, void* d_ws, size_t ws_size,
                              hipStream_t stream)
{
  const float* x     = (const float*)d_in[0];
  const float* wq    = (const float*)d_in[1];
  // d_in[2] = bq: cancelled exactly by BN mean-subtraction
  const float* gq    = (const float*)d_in[3];
  const float* betaq = (const float*)d_in[4];
  const float* wk    = (const float*)d_in[5];
  // d_in[6] = bk: cancelled
  const float* gk    = (const float*)d_in[7];
  const float* betak = (const float*)d_in[8];
  const float* wv    = (const float*)d_in[9];
  const float* bv    = (const float*)d_in[10];
  const float* wW    = (const float*)d_in[11];
  const float* bW    = (const float*)d_in[12];
  float* out = (float*)d_out;

  // workspace layout (ws_size = 256 MiB)
  char* ws = (char*)d_ws;
  unsigned short* qt   = (unsigned short*)(ws);              //  8 MiB [4*4096,256]
  unsigned short* kt   = (unsigned short*)(ws + 8388608);    //  8 MiB
  unsigned short* v    = (unsigned short*)(ws + 16777216);   //  8 MiB [4,256,4096]
  unsigned short* ctx  = (unsigned short*)(ws + 25165824);   //  8 MiB [4*4096,256]
  unsigned short* wqk  = (unsigned short*)(ws + 33554432);   // 512 KiB [512,512]
  unsigned short* wvb  = (unsigned short*)(ws + 34078720);   // 256 KiB [256,512]
  unsigned short* wWb  = (unsigned short*)(ws + 34340864);   // 256 KiB [512,256]
  float*          stat = (float*)         (ws + 34603008);   //   4 KiB
  float*          lsum = (float*)         (ws + 34607104);   //  64 KiB [4][4096]
  unsigned short* opart= (unsigned short*)(ws + 35651584);   // 32 MiB [16,4096,256] bf16
  unsigned short* xt   = (unsigned short*)(ws + 35651584);   // 16 MiB, aliases opart
  unsigned short* zt   = (unsigned short*)(ws + 52428800);   // 16 MiB, aliases opart
                                                             // (xt dead after k_qkv,
                                                             //  zt dead after k_bnrelu,
                                                             //  both before k_cx)
  unsigned short* P    = (unsigned short*)(ws + 102760448);  // 128 MiB [4,4096,4096]

  (void)hipMemsetAsync(stat, 0, 69632, stream);  // stat (4K) + lsum (64K)
  k_pre   <<<3072, 256, 0, stream>>>(x, xt, wq, wk, wv, wW, wqk, wvb, wWb);
  k_qkv   <<<dim3(32, 6, 4), 256, 0, stream>>>(xt, wqk, wvb, bv, zt, v, stat);
  k_bnrelu<<<1024, 256, 0, stream>>>(zt, stat, gq, betaq, gk, betak, qt, kt);
  k_sc    <<<dim3(32, 32, 4), 256, 0, stream>>>(qt, kt, P, lsum);
  k_cx    <<<dim3(4, 32, 8), 256, 0, stream>>>(P, v, opart);
  k_red   <<<16384, 256, 0, stream>>>(opart, lsum, ctx);
  k_out   <<<dim3(32, 4, 4), 256, 0, stream>>>(wWb, bW, ctx, x, out);
}